// Round 7
// baseline (200.913 us; speedup 1.0000x reference)
//
#include <hip/hip_runtime.h>

// Inverse SWT (db4, 3 levels), T=4096, circular boundary.
// v6: SINGLE-PASS composite-filter stencil. The 3 dilated levels compose
// (linearity) into one stencil per output:
//   out[n] = sum_s FA[s] cA[n-s] + FD3[s] cD3[n-s]   (50 taps each, s in [-21,28])
//          + sum_s FD2[s] cD2[n-s]                    (22 taps, s in [-9,12])
//          + sum_s FD1[s] cD1[n-s]                    ( 8 taps, s in [-3,4])
// Filters built constexpr in double (FA = 1/8 lo4*lo2*lo1 etc.). Removes all
// intermediate LDS round-trips and all but 2 barriers: v5 post-mortem showed
// kernel time = ~24 us HBM + ~16 us level/barrier structure; this deletes the
// structure. FMAs rise 48->130/output (~14 us VALU) but stay under the HBM
// stream; LDS reads ~42 b128/thread (~13 us) likewise.
// Staging: async global->LDS DMA, linear LDS dest + pre-swizzled global src,
// XOR slot swizzle sl(c)=c^((c>>3)&7) keeps lane-stride-2-chunk window reads
// bank-even. Counted vmcnt: cA/cD3 compute starts while cD2/cD1 stream in.

namespace {

constexpr int TT = 4096;       // time length (floats)
constexpr int T4 = TT / 4;     // float4 chunks per row
constexpr int NT = 512;        // threads per block (8 waves)

// ---- compile-time composite filters (double accumulation) ----
struct Filters {
  float fa[50];   // cA  path: (1/8) lo4 ⊛ lo2 ⊛ lo1, index = s+21
  float fd3[50];  // cD3 path: (1/8) hi4 ⊛ lo2 ⊛ lo1, index = s+21
  float fd2[22];  // cD2 path: (1/4) hi2 ⊛ lo1,        index = s+9
  float fd1[8];   // cD1 path: (1/2) hi1,              index = s+3
};

constexpr Filters make_filters() {
  const double lo[8] = {
      0.23037781330885523,  0.7148465705525415,  0.6308807679295904,
      -0.02798376941698385, -0.18703481171888114, 0.030841381835986965,
      0.032883011666982945, -0.010597401784997278};
  double hi[8] = {};
  for (int m = 0; m < 8; ++m) hi[m] = ((m & 1) ? -1.0 : 1.0) * lo[7 - m];

  double fa[50] = {}, fd3[50] = {}, fd2[22] = {};
  for (int m1 = 0; m1 < 8; ++m1)
    for (int m2 = 0; m2 < 8; ++m2)
      for (int m3 = 0; m3 < 8; ++m3) {
        const int s = 4 * (m1 - 3) + 2 * (m2 - 3) + (m3 - 3);
        fa[s + 21]  += 0.125 * lo[m1] * lo[m2] * lo[m3];
        fd3[s + 21] += 0.125 * hi[m1] * lo[m2] * lo[m3];
      }
  for (int m2 = 0; m2 < 8; ++m2)
    for (int m3 = 0; m3 < 8; ++m3)
      fd2[2 * (m2 - 3) + (m3 - 3) + 9] += 0.25 * hi[m2] * lo[m3];

  Filters f{};
  for (int i = 0; i < 50; ++i) { f.fa[i] = (float)fa[i]; f.fd3[i] = (float)fd3[i]; }
  for (int i = 0; i < 22; ++i) f.fd2[i] = (float)fd2[i];
  for (int m = 0; m < 8; ++m) f.fd1[m] = (float)(0.5 * hi[m]);
  return f;
}
constexpr Filters F = make_filters();

// Async 16B global->LDS DMA (LDS dest wave-uniform base + lane*16).
#define GLD16(gp, lp)                                                      \
  __builtin_amdgcn_global_load_lds(                                        \
      (const __attribute__((address_space(1))) void*)(gp),                 \
      (__attribute__((address_space(3))) void*)(lp), 16, 0, 0)

// XOR slot swizzle (involution, within 64-chunk blocks): bank-spreads
// lane-stride-2-chunk b128 reads. Mask also handles negative/wrapped chunks.
__device__ __forceinline__ int sl(int c) {
  c &= (T4 - 1);
  return c ^ ((c >> 3) & 7);
}

__global__ __launch_bounds__(NT, 4) void iswt_kernel(const float* __restrict__ x,
                                                     float* __restrict__ out) {
  __shared__ __align__(16) float lds_cA[TT];
  __shared__ __align__(16) float lds_h3[TT];
  __shared__ __align__(16) float lds_h2[TT];
  __shared__ __align__(16) float lds_h1[TT];   // 64 KiB -> 2 blocks/CU

  const int t = threadIdx.x;   // thread u: output chunks 2u, 2u+1 (n0 = 8u)
  const int row = blockIdx.x;  // input rows 4r..4r+3 = cA3, cD3, cD2, cD1

  const float* xr = x + (size_t)row * 4 * TT;

  // DMA-stage all 4 rows (2 chunks/thread/row). Linear LDS slot s gets global
  // chunk sl(s) (involution => LDS slot sl(c) holds chunk c). Issue order
  // cA, cD3, cD2, cD1 for the counted waits below.
#pragma unroll
  for (int k = 0; k < 2; ++k) {
    const int s = k * NT + t;
    GLD16(xr + 0 * TT + sl(s) * 4, lds_cA + s * 4);
  }
#pragma unroll
  for (int k = 0; k < 2; ++k) {
    const int s = k * NT + t;
    GLD16(xr + 1 * TT + sl(s) * 4, lds_h3 + s * 4);
  }
#pragma unroll
  for (int k = 0; k < 2; ++k) {
    const int s = k * NT + t;
    GLD16(xr + 2 * TT + sl(s) * 4, lds_h2 + s * 4);
  }
#pragma unroll
  for (int k = 0; k < 2; ++k) {
    const int s = k * NT + t;
    GLD16(xr + 3 * TT + sl(s) * 4, lds_h1 + s * 4);
  }

  float acc[8];
#pragma unroll
  for (int j = 0; j < 8; ++j) acc[j] = 0.f;

  float w[60];  // tap window, fully statically indexed (stays in VGPRs)

  // cA + cD3 landed per-wave (4 newest = cD2,cD1 may be in flight); barrier
  // makes all waves' cA/cD3 chunks visible (windows cross wave boundaries).
  asm volatile("s_waitcnt vmcnt(4)\n\ts_barrier" ::: "memory");

  const float4* cA4 = reinterpret_cast<const float4*>(lds_cA);
  const float4* h34 = reinterpret_cast<const float4*>(lds_h3);
  const float4* h24 = reinterpret_cast<const float4*>(lds_h2);
  const float4* h14 = reinterpret_cast<const float4*>(lds_h1);

  // ---- cA pass: window chunks 2u-7 .. 2u+7 (57 of 60 floats used) ----
  const int c0 = 2 * t - 7;
#pragma unroll
  for (int i = 0; i < 15; ++i) {
    const float4 v = cA4[sl(c0 + i)];
    w[4 * i + 0] = v.x; w[4 * i + 1] = v.y;
    w[4 * i + 2] = v.z; w[4 * i + 3] = v.w;
  }
#pragma unroll
  for (int ia = 0; ia < 50; ++ia) {
    const float f = F.fa[ia];
#pragma unroll
    for (int j = 0; j < 8; ++j) acc[j] += f * w[j + 49 - ia];
  }

  // ---- cD3 pass: same window geometry ----
#pragma unroll
  for (int i = 0; i < 15; ++i) {
    const float4 v = h34[sl(c0 + i)];
    w[4 * i + 0] = v.x; w[4 * i + 1] = v.y;
    w[4 * i + 2] = v.z; w[4 * i + 3] = v.w;
  }
#pragma unroll
  for (int ia = 0; ia < 50; ++ia) {
    const float f = F.fd3[ia];
#pragma unroll
    for (int j = 0; j < 8; ++j) acc[j] += f * w[j + 49 - ia];
  }

  // cD2 + cD1 landed collectively (~800 FMAs above hid their tail latency).
  asm volatile("s_waitcnt vmcnt(0)\n\ts_barrier" ::: "memory");

  // ---- cD2 pass: window chunks 2u-3 .. 2u+4 (29 of 32 floats used) ----
#pragma unroll
  for (int i = 0; i < 8; ++i) {
    const float4 v = h24[sl(2 * t - 3 + i)];
    w[4 * i + 0] = v.x; w[4 * i + 1] = v.y;
    w[4 * i + 2] = v.z; w[4 * i + 3] = v.w;
  }
#pragma unroll
  for (int ia = 0; ia < 22; ++ia) {
    const float f = F.fd2[ia];
#pragma unroll
    for (int j = 0; j < 8; ++j) acc[j] += f * w[j + 21 - ia];
  }

  // ---- cD1 pass: window chunks 2u-1 .. 2u+2 (15 of 16 floats used) ----
#pragma unroll
  for (int i = 0; i < 4; ++i) {
    const float4 v = h14[sl(2 * t - 1 + i)];
    w[4 * i + 0] = v.x; w[4 * i + 1] = v.y;
    w[4 * i + 2] = v.z; w[4 * i + 3] = v.w;
  }
#pragma unroll
  for (int ia = 0; ia < 8; ++ia) {
    const float f = F.fd1[ia];
#pragma unroll
    for (int j = 0; j < 8; ++j) acc[j] += f * w[j + 7 - ia];
  }

  // ---- store: chunks 2u, 2u+1 straight to global (L2 merges half-lines) ----
  float4* out4 = reinterpret_cast<float4*>(out) + (size_t)row * T4;
  out4[2 * t + 0] = make_float4(acc[0], acc[1], acc[2], acc[3]);
  out4[2 * t + 1] = make_float4(acc[4], acc[5], acc[6], acc[7]);
}

}  // namespace

extern "C" void kernel_launch(void* const* d_in, const int* in_sizes, int n_in,
                              void* d_out, int out_size, void* d_ws, size_t ws_size,
                              hipStream_t stream) {
  const float* x = reinterpret_cast<const float*>(d_in[0]);
  float* out = reinterpret_cast<float*>(d_out);
  const int rows = out_size / TT;  // B*N = 2048
  iswt_kernel<<<rows, NT, 0, stream>>>(x, out);
}

// Round 8
// 198.280 us; speedup vs baseline: 1.0133x; 1.0133x over previous
//
#include <hip/hip_runtime.h>

// Inverse SWT (db4, 3 levels), T=4096, circular boundary.
// v7: cross-row DMA pipeline. v0-v6 all plateau at 40-45 us kernel vs ~24 us
// HBM floor because every version phase-locks: {DMA -> barrier -> compute}
// per block, co-resident blocks in the same phase -> HBM idles under compute.
// Here each block does 4 rows; at row r start the DMA for row r+1's cA/cD3 is
// issued (counted vmcnt, never drained in-loop) so HBM streams UNDER the
// whole compute phase. cD2/cD1 skip LDS entirely: per-thread global window
// loads (neighbor threads overlap x6-8 -> L1/L2 broadcast, HBM sees each
// line once), issued right after the row barrier, consumed 1-2 phases later.
// LDS: P0/Q0/P1/Q1 = 64 KiB -> 2 blocks/CU. Per-level math identical to the
// verified v5 (same windows, same m->jc->r FMA order) -> bit-identical.

namespace {

constexpr int TT = 4096;       // time length (floats)
constexpr int T4 = TT / 4;     // float4 chunks per row
constexpr int NT = 512;        // threads per block (8 waves)
constexpr int R  = 4;          // rows per block

constexpr float LO[8] = {
    0.23037781330885523f,  0.7148465705525415f,  0.6308807679295904f,
    -0.02798376941698385f, -0.18703481171888114f, 0.030841381835986965f,
    0.032883011666982945f, -0.010597401784997278f};
constexpr float HI[8] = {
    -0.010597401784997278f, -0.032883011666982945f, 0.030841381835986965f,
    0.18703481171888114f,   -0.02798376941698385f,  -0.6308807679295904f,
    0.7148465705525415f,    -0.23037781330885523f};

// Async 16B global->LDS DMA (LDS dest wave-uniform base + lane*16).
#define GLD16(gp, lp)                                                      \
  __builtin_amdgcn_global_load_lds(                                        \
      (const __attribute__((address_space(1))) void*)(gp),                 \
      (__attribute__((address_space(3))) void*)(lp), 16, 0, 0)

// XOR slot swizzle (involution within 64-chunk groups): spreads the
// lane-stride-2-chunk b128 window reads across banks.
__device__ __forceinline__ int sl(int c) {
  c &= (T4 - 1);
  return c ^ ((c >> 3) & 7);
}

template <int W4>
__device__ __forceinline__ void lds_window(const float4* b, int c0, float* w) {
#pragma unroll
  for (int i = 0; i < W4; ++i) {
    const float4 v = b[sl(c0 + i)];
    w[4 * i + 0] = v.x; w[4 * i + 1] = v.y;
    w[4 * i + 2] = v.z; w[4 * i + 3] = v.w;
  }
}

template <int NC>
__device__ __forceinline__ void reg_window(const float4* d, float* w) {
#pragma unroll
  for (int i = 0; i < NC; ++i) {
    w[4 * i + 0] = d[i].x; w[4 * i + 1] = d[i].y;
    w[4 * i + 2] = d[i].z; w[4 * i + 3] = d[i].w;
  }
}

// acc[jc][r] += sum_m c[m] * w[D*(7-m) + 4*jc + r]  (v5's exact FMA order)
template <int D>
__device__ __forceinline__ void accum(const float* c, const float* w,
                                      float a[2][4]) {
#pragma unroll
  for (int m = 0; m < 8; ++m) {
    const int o = D * (7 - m);
#pragma unroll
    for (int jc = 0; jc < 2; ++jc)
#pragma unroll
      for (int r = 0; r < 4; ++r) a[jc][r] += c[m] * w[o + 4 * jc + r];
  }
}

// One row. VMC = counted vmcnt at the staging barrier (exact, derived from
// in-order vmcnt retirement; see call sites). PREF = issue next row's DMA.
template <int VMC, bool PREF>
__device__ __forceinline__ void do_row(const float* xrow, const float* xnext,
                                       float* Pc, float* Qc, float* Pn,
                                       float* Qn, float* outrow, int t) {
  const float4* P4 = reinterpret_cast<const float4*>(Pc);
  const float4* Q4 = reinterpret_cast<const float4*>(Qc);
  float4* Pw = reinterpret_cast<float4*>(Pc);

  // b0: all waves done reading Pn/Qn (previous round) -> safe to DMA-fill.
  asm volatile("s_waitcnt lgkmcnt(0)\n\ts_barrier" ::: "memory");
  if constexpr (PREF) {
#pragma unroll
    for (int k = 0; k < 2; ++k) {
      const int s = k * NT + t;
      GLD16(xnext + 0 * TT + sl(s) * 4, Pn + s * 4);
    }
#pragma unroll
    for (int k = 0; k < 2; ++k) {
      const int s = k * NT + t;
      GLD16(xnext + 1 * TT + sl(s) * 4, Qn + s * 4);
    }
  }
  // b1: this row's cA (->Pc) and cD3 (->Qc) landed in every wave. Counted:
  // everything older than the VMC newest vmem ops is retired.
  asm volatile("s_waitcnt vmcnt(%0)\n\ts_barrier" ::"n"(VMC) : "memory");

  // cD2/cD1 register windows, issued now, consumed 1-2 phases later
  // (HBM latency hides under level-3 compute; compiler inserts the use-wait).
  const float4* g2 = reinterpret_cast<const float4*>(xrow + 2 * TT);
  const float4* g1 = reinterpret_cast<const float4*>(xrow + 3 * TT);
  float4 d2[6], d1[4];
#pragma unroll
  for (int i = 0; i < 6; ++i) d2[i] = g2[(2 * t - 2 + i) & (T4 - 1)];
#pragma unroll
  for (int i = 0; i < 4; ++i) d1[i] = g1[(2 * t - 1 + i) & (T4 - 1)];

  float w[36];
  float a[2][4] = {{0.f, 0.f, 0.f, 0.f}, {0.f, 0.f, 0.f, 0.f}};

  // ---- level 3 (D=4): res=cA(LDS), hi=cD3(LDS) ----
  lds_window<9>(P4, 2 * t - 4, w);
  accum<4>(LO, w, a);
  lds_window<9>(Q4, 2 * t - 4, w);
  accum<4>(HI, w, a);
  float4 r0 = make_float4(0.5f * a[0][0], 0.5f * a[0][1], 0.5f * a[0][2],
                          0.5f * a[0][3]);
  float4 r1 = make_float4(0.5f * a[1][0], 0.5f * a[1][1], 0.5f * a[1][2],
                          0.5f * a[1][3]);

  asm volatile("s_waitcnt lgkmcnt(0)\n\ts_barrier" ::: "memory");  // b2
  Pw[sl(2 * t)] = r0;
  Pw[sl(2 * t + 1)] = r1;
  asm volatile("s_waitcnt lgkmcnt(0)\n\ts_barrier" ::: "memory");  // b3

  // ---- level 2 (D=2): res(LDS), hi=cD2(regs) ----
#pragma unroll
  for (int jc = 0; jc < 2; ++jc)
#pragma unroll
    for (int r = 0; r < 4; ++r) a[jc][r] = 0.f;
  lds_window<6>(P4, 2 * t - 2, w);
  accum<2>(LO, w, a);
  reg_window<6>(d2, w);
  accum<2>(HI, w, a);
  r0 = make_float4(0.5f * a[0][0], 0.5f * a[0][1], 0.5f * a[0][2],
                   0.5f * a[0][3]);
  r1 = make_float4(0.5f * a[1][0], 0.5f * a[1][1], 0.5f * a[1][2],
                   0.5f * a[1][3]);

  asm volatile("s_waitcnt lgkmcnt(0)\n\ts_barrier" ::: "memory");  // b4
  Pw[sl(2 * t)] = r0;
  Pw[sl(2 * t + 1)] = r1;
  asm volatile("s_waitcnt lgkmcnt(0)\n\ts_barrier" ::: "memory");  // b5

  // ---- level 1 (D=1): res(LDS), hi=cD1(regs); straight to global ----
#pragma unroll
  for (int jc = 0; jc < 2; ++jc)
#pragma unroll
    for (int r = 0; r < 4; ++r) a[jc][r] = 0.f;
  lds_window<4>(P4, 2 * t - 1, w);
  accum<1>(LO, w, a);
  reg_window<4>(d1, w);
  accum<1>(HI, w, a);

  float4* out4 = reinterpret_cast<float4*>(outrow);
  out4[2 * t + 0] = make_float4(0.5f * a[0][0], 0.5f * a[0][1],
                                0.5f * a[0][2], 0.5f * a[0][3]);
  out4[2 * t + 1] = make_float4(0.5f * a[1][0], 0.5f * a[1][1],
                                0.5f * a[1][2], 0.5f * a[1][3]);
}

__global__ __launch_bounds__(NT, 4) void iswt_kernel(const float* __restrict__ x,
                                                     float* __restrict__ out) {
  __shared__ __align__(16) float P0[TT], Q0[TT], P1[TT], Q1[TT];  // 64 KiB

  const int t = threadIdx.x;
  const size_t blk = blockIdx.x;  // handles rows 4*blk .. 4*blk+3

  const float* xg = x + blk * (size_t)(R * 4 * TT);
  float* og = out + blk * (size_t)(R * TT);

  // Prologue: DMA row 0's cA->P0, cD3->Q0 (4 ops).
#pragma unroll
  for (int k = 0; k < 2; ++k) {
    const int s = k * NT + t;
    GLD16(xg + 0 * TT + sl(s) * 4, P0 + s * 4);
  }
#pragma unroll
  for (int k = 0; k < 2; ++k) {
    const int s = k * NT + t;
    GLD16(xg + 1 * TT + sl(s) * 4, Q0 + s * 4);
  }

  // vmcnt accounting (in-order retirement): at row r's b1 the ops newer than
  // row r's own DMA are: r0: DMA(1)=4 -> 4; middle: d2(r-1)6 + d1(r-1)4 +
  // st(r-1)4 + DMA(r+1)4 -> 18; last (no PREF): 6+4+4 -> 14.
  do_row<4,  true >(xg + 0 * 4 * TT, xg + 1 * 4 * TT, P0, Q0, P1, Q1,
                    og + 0 * TT, t);
  do_row<18, true >(xg + 1 * 4 * TT, xg + 2 * 4 * TT, P1, Q1, P0, Q0,
                    og + 1 * TT, t);
  do_row<18, true >(xg + 2 * 4 * TT, xg + 3 * 4 * TT, P0, Q0, P1, Q1,
                    og + 2 * TT, t);
  do_row<14, false>(xg + 3 * 4 * TT, nullptr,          P1, Q1, P0, Q0,
                    og + 3 * TT, t);
}

}  // namespace

extern "C" void kernel_launch(void* const* d_in, const int* in_sizes, int n_in,
                              void* d_out, int out_size, void* d_ws, size_t ws_size,
                              hipStream_t stream) {
  const float* x = reinterpret_cast<const float*>(d_in[0]);
  float* out = reinterpret_cast<float*>(d_out);
  const int rows = out_size / TT;  // B*N = 2048
  iswt_kernel<<<rows / R, NT, 0, stream>>>(x, out);
}